// Round 1
// baseline (880.098 us; speedup 1.0000x reference)
//
#include <hip/hip_runtime.h>
#include <hip/hip_bf16.h>

typedef __hip_bfloat16 bf16;
typedef __attribute__((ext_vector_type(4))) float f32x4;
typedef __attribute__((ext_vector_type(8))) short bs8;

#define B_  8
#define C_  512
#define N_  4096
#define CQ_ 64

#define MFMA16(a, b, c) __builtin_amdgcn_mfma_f32_16x16x32_bf16(a, b, c, 0, 0, 0)

// ---------------------------------------------------------------------------
// Fused weight cast: Wq (8192 f4) + Wk (8192 f4) + Wv (65536 f4) in one launch
// ---------------------------------------------------------------------------
__global__ __launch_bounds__(256) void cast_weights(
    const float* __restrict__ wq, const float* __restrict__ wk,
    const float* __restrict__ wv,
    bf16* __restrict__ dq, bf16* __restrict__ dk, bf16* __restrict__ dv)
{
    int i = blockIdx.x * 256 + threadIdx.x;
    const float* src;
    bf16* dst;
    int off;
    if (i < 8192)       { src = wq; dst = dq; off = i; }
    else if (i < 16384) { src = wk; dst = dk; off = i - 8192; }
    else if (i < 81920) { src = wv; dst = dv; off = i - 16384; }
    else return;
    float4 v = *(const float4*)(src + (size_t)off * 4);
    union { bf16 h[4]; uint2 u; } pk;
    pk.h[0] = __float2bfloat16(v.x);
    pk.h[1] = __float2bfloat16(v.y);
    pk.h[2] = __float2bfloat16(v.z);
    pk.h[3] = __float2bfloat16(v.w);
    *(uint2*)(dst + (size_t)off * 4) = pk.u;
}

// ---------------------------------------------------------------------------
// x [B][C][N] fp32 -> xT [B][N][C] bf16  (64c x 64n tiles via LDS)
// ---------------------------------------------------------------------------
__global__ __launch_bounds__(256) void cast_transpose(
    const float* __restrict__ x, bf16* __restrict__ xT)
{
    const int b = blockIdx.z, c0 = blockIdx.y * 64, n0 = blockIdx.x * 64;
    const int t = threadIdx.x;
    __shared__ bf16 tile[64][72];   // [n][c]

    const float* xb = x + ((size_t)b * C_ + c0) * N_ + n0;
    const int cr = t >> 4;
    const int nc4 = (t & 15) * 4;
#pragma unroll
    for (int r = 0; r < 4; r++) {
        int c = cr + r * 16;
        float4 v = *(const float4*)&xb[(size_t)c * N_ + nc4];
        tile[nc4 + 0][c] = __float2bfloat16(v.x);
        tile[nc4 + 1][c] = __float2bfloat16(v.y);
        tile[nc4 + 2][c] = __float2bfloat16(v.z);
        tile[nc4 + 3][c] = __float2bfloat16(v.w);
    }
    __syncthreads();

    bf16* dst = xT + ((size_t)b * N_ + n0) * C_ + c0;
#pragma unroll
    for (int rep = 0; rep < 2; rep++) {
        int idx = t + rep * 256;
        int row = idx >> 3, seg = idx & 7;
        *(uint4*)&dst[(size_t)row * C_ + seg * 8] = *(uint4*)&tile[row][seg * 8];
    }
}

// ---------------------------------------------------------------------------
// MFMA projection GEMM: D[o][n] = sum_c W[o][c] * xT[n][c] (+bias[o])
// MODE 0: out[n][64] bf16 (Q/K, o0==0).  MODE 1: out[o][N] bf16 (Vt).
// ---------------------------------------------------------------------------
template <int MODE>
__global__ __launch_bounds__(256, 4) void mfma_gemm(
    const bf16* __restrict__ xT, const bf16* __restrict__ Wb,
    const float* __restrict__ bias, bf16* __restrict__ out)
{
    const int b = blockIdx.z, n0 = blockIdx.x * 64, o0 = blockIdx.y * 64;
    const int t = threadIdx.x;
    const int wave = t >> 6, lane = t & 63, quad = lane >> 4, l16 = lane & 15;
    __shared__ bf16 st[64][72];

    const bf16* Arow = Wb + (size_t)(o0 + wave * 16 + l16) * C_ + quad * 8;
    const bf16* Brow = xT + ((size_t)b * N_ + n0 + l16) * C_ + quad * 8;

    f32x4 acc[4];
#pragma unroll
    for (int nc = 0; nc < 4; nc++) acc[nc] = (f32x4){0.f, 0.f, 0.f, 0.f};

    bs8 a_cur = *(const bs8*)Arow;
    bs8 b_cur[4];
#pragma unroll
    for (int nc = 0; nc < 4; nc++)
        b_cur[nc] = *(const bs8*)(Brow + (size_t)nc * 16 * C_);

#pragma unroll
    for (int c0 = 0; c0 < C_; c0 += 32) {
        bs8 a_nxt;
        bs8 b_nxt[4];
        if (c0 + 32 < C_) {
            a_nxt = *(const bs8*)(Arow + c0 + 32);
#pragma unroll
            for (int nc = 0; nc < 4; nc++)
                b_nxt[nc] = *(const bs8*)(Brow + (size_t)nc * 16 * C_ + c0 + 32);
        }
#pragma unroll
        for (int nc = 0; nc < 4; nc++)
            acc[nc] = MFMA16(a_cur, b_cur[nc], acc[nc]);
        a_cur = a_nxt;
#pragma unroll
        for (int nc = 0; nc < 4; nc++) b_cur[nc] = b_nxt[nc];
    }

    float bias_r[4];
#pragma unroll
    for (int r = 0; r < 4; r++)
        bias_r[r] = bias[o0 + wave * 16 + quad * 4 + r];

#pragma unroll
    for (int nc = 0; nc < 4; nc++)
#pragma unroll
        for (int r = 0; r < 4; r++) {
            bf16 hv = __float2bfloat16(acc[nc][r] + bias_r[r]);
            if (MODE == 0)
                st[nc * 16 + l16][wave * 16 + quad * 4 + r] = hv;
            else
                st[wave * 16 + quad * 4 + r][nc * 16 + l16] = hv;
        }
    __syncthreads();

#pragma unroll
    for (int rep = 0; rep < 2; rep++) {
        int idx = t + rep * 256;
        int row = idx >> 3, seg = idx & 7;
        uint4 v = *(uint4*)&st[row][seg * 8];
        if (MODE == 0)
            *(uint4*)&out[((size_t)b * N_ + n0 + row) * CQ_ + seg * 8] = v;
        else
            *(uint4*)&out[((size_t)b * C_ + o0 + row) * N_ + n0 + seg * 8] = v;
    }
}

// ---------------------------------------------------------------------------
// Fused attention, restructured for occupancy:
//  512 threads / 8 waves, 32 i-rows per block, 64 channels per wave.
//  oacc[2][4]=32 VGPR, target <=128 total -> 4 waves/SIMD (2 blocks/CU).
//  Wave w: S subtile (rc=w&1, cc=w>>1); PV channels ch0=w*64.
//  One barrier per jt; P double-buffered in LDS with 16B-xor swizzle.
//  Math order per output element identical to previous kernel.
// ---------------------------------------------------------------------------
__global__ __launch_bounds__(512, 4) void attn_fused(
    const bf16* __restrict__ Qg, const bf16* __restrict__ Kg,
    const bf16* __restrict__ Vt, const float* __restrict__ x,
    const float* __restrict__ gamma, float* __restrict__ out)
{
    const int b    = blockIdx.x;          // grid.x = batch -> XCD affinity
    const int i0   = blockIdx.y * 32;
    const int t    = threadIdx.x;
    const int wave = t >> 6;              // 0..7
    const int lane = t & 63;
    const int quad = lane >> 4;
    const int l16  = lane & 15;
    const int rc   = wave & 1;            // S row-chunk (16 rows)
    const int cc   = wave >> 1;           // S col-chunk (16 j)
    const int ch0  = wave * 64;           // PV channel base

    // LDS: Q [0,4K), P dbuf [4K,12K). 128B rows, 16B-block xor swizzle.
    __shared__ char lds[12288];

    {   // stage Q tile (32 x 64 bf16), 8B per thread
        const int r   = t >> 4;           // 0..31
        const int seg = t & 15;           // 8B segment in 128B row
        const bf16* src = Qg + ((size_t)b * N_ + i0 + r) * CQ_ + seg * 4;
        uint2 v = *(const uint2*)src;
        int bi = seg >> 1;                // 16B block index
        *(uint2*)(lds + r * 128 + ((bi ^ (r & 7)) << 4) + (seg & 1) * 8) = v;
    }

    bs8 ones;
#pragma unroll
    for (int e = 0; e < 8; e++) ones[e] = (short)0x3F80;

    f32x4 oacc[2][4];
#pragma unroll
    for (int s = 0; s < 2; s++)
#pragma unroll
        for (int c = 0; c < 4; c++) oacc[s][c] = (f32x4){0.f, 0.f, 0.f, 0.f};
    f32x4 lacc[2];
#pragma unroll
    for (int s = 0; s < 2; s++) lacc[s] = (f32x4){0.f, 0.f, 0.f, 0.f};

    const bf16* Kbase = Kg + ((size_t)b * N_ + cc * 16 + l16) * CQ_ + quad * 8;
    const bf16* Vbase = Vt + ((size_t)b * C_ + ch0 + l16) * (size_t)N_ + quad * 8;

    bs8 kb0 = *(const bs8*)(Kbase);
    bs8 kb1 = *(const bs8*)(Kbase + 32);

    __syncthreads();   // Q staged

    for (int jt = 0; jt < 64; jt++) {
        const int j0 = jt * 64;
        const bf16* vj = Vbase + j0;

        // V prefetch ct0,ct1 (depth-2 circular)
        bs8 vb[2][2];
        vb[0][0] = *(const bs8*)(vj);
        vb[0][1] = *(const bs8*)(vj + 32);
        vb[1][0] = *(const bs8*)(vj + (size_t)16 * N_);
        vb[1][1] = *(const bs8*)(vj + (size_t)16 * N_ + 32);

        // next-tile K prefetch
        bs8 nk0, nk1;
        if (jt < 63) {
            nk0 = *(const bs8*)(Kbase + (size_t)(j0 + 64) * CQ_);
            nk1 = *(const bs8*)(Kbase + (size_t)(j0 + 64) * CQ_ + 32);
        }

        // S subtile: rows i0+rc*16.., cols j0+cc*16..
        const int qr = rc * 16 + l16;
        bs8 qa0 = *(const bs8*)(lds + qr * 128 + (((quad    ) ^ (qr & 7)) << 4));
        bs8 qa1 = *(const bs8*)(lds + qr * 128 + (((quad + 4) ^ (qr & 7)) << 4));
        f32x4 z = (f32x4){0.f, 0.f, 0.f, 0.f};
        z = MFMA16(qa0, kb0, z);
        z = MFMA16(qa1, kb1, z);

        // P = exp(S) -> double-buffered LDS (4 scalar b16 writes/lane)
        char* pbuf = lds + 4096 + (jt & 1) * 4096;
#pragma unroll
        for (int reg = 0; reg < 4; reg++) {
            int row = rc * 16 + quad * 4 + reg;
            int col = cc * 16 + l16;
            bf16 h = __float2bfloat16(__expf(z[reg]));
            *(short*)(pbuf + row * 128 +
                      ((((col >> 3) ^ (row & 7)) << 4)) + (col & 7) * 2) = *(short*)&h;
        }
        __syncthreads();   // P ready (single barrier per jt)

        // P A-frags + l accumulation
        bs8 pa0[2], pa1[2];
#pragma unroll
        for (int sub = 0; sub < 2; sub++) {
            int pr = sub * 16 + l16;
            pa0[sub] = *(const bs8*)(pbuf + pr * 128 + (((quad    ) ^ (pr & 7)) << 4));
            pa1[sub] = *(const bs8*)(pbuf + pr * 128 + (((quad + 4) ^ (pr & 7)) << 4));
            lacc[sub] = MFMA16(pa0[sub], ones, lacc[sub]);
            lacc[sub] = MFMA16(pa1[sub], ones, lacc[sub]);
        }

        // O += P.V  (4 ct of 16 channels, depth-2 circular V prefetch)
        __builtin_amdgcn_s_setprio(1);
#pragma unroll
        for (int ct = 0; ct < 4; ct++) {
            bs8 v0 = vb[ct & 1][0], v1 = vb[ct & 1][1];
            if (ct < 2) {
                vb[ct & 1][0] = *(const bs8*)(vj + (size_t)(ct + 2) * 16 * N_);
                vb[ct & 1][1] = *(const bs8*)(vj + (size_t)(ct + 2) * 16 * N_ + 32);
            }
#pragma unroll
            for (int sub = 0; sub < 2; sub++) {
                oacc[sub][ct] = MFMA16(pa0[sub], v0, oacc[sub][ct]);
                oacc[sub][ct] = MFMA16(pa1[sub], v1, oacc[sub][ct]);
            }
        }
        __builtin_amdgcn_s_setprio(0);

        kb0 = nk0; kb1 = nk1;
    }

    // ---- epilogue: out = gamma*O/l + x ----
    const float g = gamma[0];
#pragma unroll
    for (int sub = 0; sub < 2; sub++) {
        float inv0 = g / lacc[sub][0];
        float inv1 = g / lacc[sub][1];
        float inv2 = g / lacc[sub][2];
        float inv3 = g / lacc[sub][3];
#pragma unroll
        for (int ct = 0; ct < 4; ct++) {
            int c = ch0 + ct * 16 + l16;
            int n = i0 + sub * 16 + quad * 4;
            size_t idx = ((size_t)b * C_ + c) * N_ + n;
            float4 xv = *(const float4*)(x + idx);
            float4 o;
            o.x = oacc[sub][ct][0] * inv0 + xv.x;
            o.y = oacc[sub][ct][1] * inv1 + xv.y;
            o.z = oacc[sub][ct][2] * inv2 + xv.z;
            o.w = oacc[sub][ct][3] * inv3 + xv.w;
            *(float4*)(out + idx) = o;
        }
    }
}

// ---------------------------------------------------------------------------
extern "C" void kernel_launch(void* const* d_in, const int* in_sizes, int n_in,
                              void* d_out, int out_size, void* d_ws, size_t ws_size,
                              hipStream_t stream)
{
    const float* x     = (const float*)d_in[0];
    const float* Wq    = (const float*)d_in[1];
    const float* bq    = (const float*)d_in[2];
    const float* Wk    = (const float*)d_in[3];
    const float* bk    = (const float*)d_in[4];
    const float* Wv    = (const float*)d_in[5];
    const float* bv    = (const float*)d_in[6];
    const float* gamma = (const float*)d_in[7];
    float* out = (float*)d_out;

    dim3 blk(256);
    dim3 blk512(512);

    const size_t szXT = (size_t)B_ * N_ * C_ * sizeof(bf16);   // 33,554,432
    const size_t szQ  = (size_t)B_ * N_ * CQ_ * sizeof(bf16);  //  4,194,304
    const size_t szVt = szXT;                                  // 33,554,432
    const size_t szWq = (size_t)CQ_ * C_ * sizeof(bf16);       //     65,536
    const size_t szWv = (size_t)C_ * C_ * sizeof(bf16);        //    524,288
    const size_t need_full = szXT + 2 * szQ + szVt + 2 * szWq + szWv; // ~72.6 MB

    if (ws_size >= need_full) {
        char* ws = (char*)d_ws;
        bf16* xT  = (bf16*)ws;
        bf16* Q   = (bf16*)(ws + szXT);
        bf16* K   = (bf16*)(ws + szXT + szQ);
        bf16* Vt  = (bf16*)(ws + szXT + 2 * szQ);
        bf16* Wqb = (bf16*)(ws + szXT + 2 * szQ + szVt);
        bf16* Wkb = (bf16*)((char*)Wqb + szWq);
        bf16* Wvb = (bf16*)((char*)Wkb + szWq);

        cast_weights<<<dim3(320), blk, 0, stream>>>(Wq, Wk, Wv, Wqb, Wkb, Wvb);
        cast_transpose<<<dim3(64, 8, B_), blk, 0, stream>>>(x, xT);

        mfma_gemm<0><<<dim3(64, 1, B_), blk, 0, stream>>>(xT, Wqb, bq, Q);
        mfma_gemm<0><<<dim3(64, 1, B_), blk, 0, stream>>>(xT, Wkb, bk, K);
        mfma_gemm<1><<<dim3(64, 8, B_), blk, 0, stream>>>(xT, Wvb, bv, Vt);

        attn_fused<<<dim3(B_, 128), blk512, 0, stream>>>(Q, K, Vt, x, gamma, out);
    } else {
        // Per-batch chunked fallback
        const size_t xtb = (size_t)N_ * C_ * sizeof(bf16);
        const size_t qb  = (size_t)N_ * CQ_ * sizeof(bf16);
        char* ws = (char*)d_ws;
        bf16* Wqb = (bf16*)ws;
        bf16* Wkb = (bf16*)(ws + szWq);
        bf16* Wvb = (bf16*)(ws + 2 * szWq);
        bf16* xT  = (bf16*)(ws + 2 * szWq + szWv);
        bf16* Q   = (bf16*)((char*)xT + xtb);
        bf16* K   = (bf16*)((char*)Q + qb);
        bf16* Vt  = (bf16*)((char*)K + qb);

        cast_weights<<<dim3(320), blk, 0, stream>>>(Wq, Wk, Wv, Wqb, Wkb, Wvb);

        for (int b = 0; b < B_; b++) {
            const float* xb = x + (size_t)b * C_ * N_;
            float*       ob = out + (size_t)b * C_ * N_;
            cast_transpose<<<dim3(64, 8, 1), blk, 0, stream>>>(xb, xT);
            mfma_gemm<0><<<dim3(64, 1, 1), blk, 0, stream>>>(xT, Wqb, bq, Q);
            mfma_gemm<0><<<dim3(64, 1, 1), blk, 0, stream>>>(xT, Wkb, bk, K);
            mfma_gemm<1><<<dim3(64, 8, 1), blk, 0, stream>>>(xT, Wvb, bv, Vt);
            attn_fused<<<dim3(1, 128), blk512, 0, stream>>>(Q, K, Vt, xb, gamma, ob);
        }
    }
}

// Round 2
// 602.522 us; speedup vs baseline: 1.4607x; 1.4607x over previous
//
#include <hip/hip_runtime.h>
#include <hip/hip_bf16.h>

typedef __hip_bfloat16 bf16;
typedef __attribute__((ext_vector_type(4))) float f32x4;
typedef __attribute__((ext_vector_type(8))) short bs8;

#define B_  8
#define C_  512
#define N_  4096
#define CQ_ 64

#define MFMA16(a, b, c) __builtin_amdgcn_mfma_f32_16x16x32_bf16(a, b, c, 0, 0, 0)

// ---------------------------------------------------------------------------
// Fused weight cast: Wq (8192 f4) + Wk (8192 f4) + Wv (65536 f4) in one launch
// ---------------------------------------------------------------------------
__global__ __launch_bounds__(256) void cast_weights(
    const float* __restrict__ wq, const float* __restrict__ wk,
    const float* __restrict__ wv,
    bf16* __restrict__ dq, bf16* __restrict__ dk, bf16* __restrict__ dv)
{
    int i = blockIdx.x * 256 + threadIdx.x;
    const float* src;
    bf16* dst;
    int off;
    if (i < 8192)       { src = wq; dst = dq; off = i; }
    else if (i < 16384) { src = wk; dst = dk; off = i - 8192; }
    else if (i < 81920) { src = wv; dst = dv; off = i - 16384; }
    else return;
    float4 v = *(const float4*)(src + (size_t)off * 4);
    union { bf16 h[4]; uint2 u; } pk;
    pk.h[0] = __float2bfloat16(v.x);
    pk.h[1] = __float2bfloat16(v.y);
    pk.h[2] = __float2bfloat16(v.z);
    pk.h[3] = __float2bfloat16(v.w);
    *(uint2*)(dst + (size_t)off * 4) = pk.u;
}

// ---------------------------------------------------------------------------
// x [B][C][N] fp32 -> xT [B][N][C] bf16  (64c x 64n tiles via LDS)
// ---------------------------------------------------------------------------
__global__ __launch_bounds__(256) void cast_transpose(
    const float* __restrict__ x, bf16* __restrict__ xT)
{
    const int b = blockIdx.z, c0 = blockIdx.y * 64, n0 = blockIdx.x * 64;
    const int t = threadIdx.x;
    __shared__ bf16 tile[64][72];   // [n][c]

    const float* xb = x + ((size_t)b * C_ + c0) * N_ + n0;
    const int cr = t >> 4;
    const int nc4 = (t & 15) * 4;
#pragma unroll
    for (int r = 0; r < 4; r++) {
        int c = cr + r * 16;
        float4 v = *(const float4*)&xb[(size_t)c * N_ + nc4];
        tile[nc4 + 0][c] = __float2bfloat16(v.x);
        tile[nc4 + 1][c] = __float2bfloat16(v.y);
        tile[nc4 + 2][c] = __float2bfloat16(v.z);
        tile[nc4 + 3][c] = __float2bfloat16(v.w);
    }
    __syncthreads();

    bf16* dst = xT + ((size_t)b * N_ + n0) * C_ + c0;
#pragma unroll
    for (int rep = 0; rep < 2; rep++) {
        int idx = t + rep * 256;
        int row = idx >> 3, seg = idx & 7;
        *(uint4*)&dst[(size_t)row * C_ + seg * 8] = *(uint4*)&tile[row][seg * 8];
    }
}

// ---------------------------------------------------------------------------
// MFMA projection GEMM: D[o][n] = sum_c W[o][c] * xT[n][c] (+bias[o])
// MODE 0: out[n][64] bf16 (Q/K, o0==0).  MODE 1: out[o][N] bf16 (Vt).
// ---------------------------------------------------------------------------
template <int MODE>
__global__ __launch_bounds__(256, 4) void mfma_gemm(
    const bf16* __restrict__ xT, const bf16* __restrict__ Wb,
    const float* __restrict__ bias, bf16* __restrict__ out)
{
    const int b = blockIdx.z, n0 = blockIdx.x * 64, o0 = blockIdx.y * 64;
    const int t = threadIdx.x;
    const int wave = t >> 6, lane = t & 63, quad = lane >> 4, l16 = lane & 15;
    __shared__ bf16 st[64][72];

    const bf16* Arow = Wb + (size_t)(o0 + wave * 16 + l16) * C_ + quad * 8;
    const bf16* Brow = xT + ((size_t)b * N_ + n0 + l16) * C_ + quad * 8;

    f32x4 acc[4];
#pragma unroll
    for (int nc = 0; nc < 4; nc++) acc[nc] = (f32x4){0.f, 0.f, 0.f, 0.f};

    bs8 a_cur = *(const bs8*)Arow;
    bs8 b_cur[4];
#pragma unroll
    for (int nc = 0; nc < 4; nc++)
        b_cur[nc] = *(const bs8*)(Brow + (size_t)nc * 16 * C_);

#pragma unroll
    for (int c0 = 0; c0 < C_; c0 += 32) {
        bs8 a_nxt;
        bs8 b_nxt[4];
        if (c0 + 32 < C_) {
            a_nxt = *(const bs8*)(Arow + c0 + 32);
#pragma unroll
            for (int nc = 0; nc < 4; nc++)
                b_nxt[nc] = *(const bs8*)(Brow + (size_t)nc * 16 * C_ + c0 + 32);
        }
#pragma unroll
        for (int nc = 0; nc < 4; nc++)
            acc[nc] = MFMA16(a_cur, b_cur[nc], acc[nc]);
        a_cur = a_nxt;
#pragma unroll
        for (int nc = 0; nc < 4; nc++) b_cur[nc] = b_nxt[nc];
    }

    float bias_r[4];
#pragma unroll
    for (int r = 0; r < 4; r++)
        bias_r[r] = bias[o0 + wave * 16 + quad * 4 + r];

#pragma unroll
    for (int nc = 0; nc < 4; nc++)
#pragma unroll
        for (int r = 0; r < 4; r++) {
            bf16 hv = __float2bfloat16(acc[nc][r] + bias_r[r]);
            if (MODE == 0)
                st[nc * 16 + l16][wave * 16 + quad * 4 + r] = hv;
            else
                st[wave * 16 + quad * 4 + r][nc * 16 + l16] = hv;
        }
    __syncthreads();

#pragma unroll
    for (int rep = 0; rep < 2; rep++) {
        int idx = t + rep * 256;
        int row = idx >> 3, seg = idx & 7;
        uint4 v = *(uint4*)&st[row][seg * 8];
        if (MODE == 0)
            *(uint4*)&out[((size_t)b * N_ + n0 + row) * CQ_ + seg * 8] = v;
        else
            *(uint4*)&out[((size_t)b * C_ + o0 + row) * N_ + n0 + seg * 8] = v;
    }
}

// ---------------------------------------------------------------------------
// Fused attention — round-0 structure (64 i-rows, 4 waves, 64-j tiles, one
// barrier per jt) but channel-SPLIT 2x via blockIdx.z: each block owns 256
// output channels -> oacc[4][4]=64 acc regs (total ~200/wave) ->
// __launch_bounds__(256,2) gives 2 blocks/CU (vs 1 before).
// S/exp/P/l phases are duplicated across the two z-blocks (cheap: 16/48 MFMA);
// V traffic is split, not duplicated.  Entire per-iter V working set
// prefetches up front and hides under the S+exp+barrier phase.
// ---------------------------------------------------------------------------
__global__ __launch_bounds__(256, 2) void attn_fused(
    const bf16* __restrict__ Qg, const bf16* __restrict__ Kg,
    const bf16* __restrict__ Vt, const float* __restrict__ x,
    const float* __restrict__ gamma, float* __restrict__ out)
{
    const int b    = blockIdx.x;          // batch -> XCD affinity
    const int i0   = blockIdx.y * 64;
    const int ch0  = blockIdx.z * 256;    // channel half
    const int t    = threadIdx.x;
    const int wave = t >> 6;
    const int lane = t & 63;
    const int quad = lane >> 4;
    const int l16  = lane & 15;

    // LDS: Q [0,8K), P0 [8K,16K), P1 [16K,24K). 128B rows, 16B-block xor swizzle.
    __shared__ char lds[24576];

    {   // stage Q tile (64 x 64 bf16)
        const int r  = t >> 2;
        const int bi = (t & 3) * 2;
        const bf16* src = Qg + ((size_t)b * N_ + i0 + r) * CQ_ + bi * 8;
        uint4 v0 = *(const uint4*)(src);
        uint4 v1 = *(const uint4*)(src + 8);
        *(uint4*)(lds + r * 128 + (((bi    ) ^ (r & 7)) << 4)) = v0;
        *(uint4*)(lds + r * 128 + (((bi + 1) ^ (r & 7)) << 4)) = v1;
    }

    bs8 ones;
#pragma unroll
    for (int e = 0; e < 8; e++) ones[e] = (short)0x3F80;

    f32x4 oacc[4][4];
#pragma unroll
    for (int s = 0; s < 4; s++)
#pragma unroll
        for (int c = 0; c < 4; c++) oacc[s][c] = (f32x4){0.f, 0.f, 0.f, 0.f};
    f32x4 lacc[4];
#pragma unroll
    for (int s = 0; s < 4; s++) lacc[s] = (f32x4){0.f, 0.f, 0.f, 0.f};

    const bf16* Kbase = Kg + ((size_t)b * N_ + wave * 16 + l16) * CQ_ + quad * 8;
    const bf16* Vbase = Vt + ((size_t)(b * C_ + ch0 + wave * 64 + l16)) * (size_t)N_ + quad * 8;

    bs8 kb0 = *(const bs8*)(Kbase);
    bs8 kb1 = *(const bs8*)(Kbase + 32);

    __syncthreads();   // Q staged

    for (int jt = 0; jt < 64; jt++) {
        const int j0 = jt * 64;
        const bf16* vj = Vbase + j0;

        // Full V working set for this iter (4 ct x 16 ch x 64 j), issued up
        // front -> latency hides under S + exp + barrier phase.
        bs8 vb[4][2];
#pragma unroll
        for (int p = 0; p < 4; p++) {
            vb[p][0] = *(const bs8*)(vj + (size_t)p * 16 * N_);
            vb[p][1] = *(const bs8*)(vj + (size_t)p * 16 * N_ + 32);
        }
        // next-tile K prefetch
        bs8 nk0, nk1;
        if (jt < 63) {
            nk0 = *(const bs8*)(Kbase + (size_t)(j0 + 64) * CQ_);
            nk1 = *(const bs8*)(Kbase + (size_t)(j0 + 64) * CQ_ + 32);
        }

        // S = Q.K^T  (rows i0..i0+63, cols j0+wave*16..+16)
        f32x4 sacc[4];
#pragma unroll
        for (int sub = 0; sub < 4; sub++) {
            int r = sub * 16 + l16;
            bs8 qa0 = *(const bs8*)(lds + r * 128 + (((quad    ) ^ (r & 7)) << 4));
            bs8 qa1 = *(const bs8*)(lds + r * 128 + (((quad + 4) ^ (r & 7)) << 4));
            f32x4 z = (f32x4){0.f, 0.f, 0.f, 0.f};
            z = MFMA16(qa0, kb0, z);
            z = MFMA16(qa1, kb1, z);
            sacc[sub] = z;
        }

        // P = exp(S) -> double-buffered LDS (no pre-write barrier needed)
        char* pbuf = lds + 8192 + (jt & 1) * 8192;
#pragma unroll
        for (int sub = 0; sub < 4; sub++) {
#pragma unroll
            for (int reg = 0; reg < 4; reg++) {
                int row = sub * 16 + quad * 4 + reg;
                int col = wave * 16 + l16;
                bf16 h = __float2bfloat16(__expf(sacc[sub][reg]));
                *(short*)(pbuf + row * 128 +
                          ((((col >> 3) ^ (row & 7)) << 4)) + (col & 7) * 2) = *(short*)&h;
            }
        }
        __syncthreads();   // P ready (single barrier per jt)

        // P A-frags + l accumulation
        bs8 pa0[4], pa1[4];
#pragma unroll
        for (int sub = 0; sub < 4; sub++) {
            int r = sub * 16 + l16;
            pa0[sub] = *(const bs8*)(pbuf + r * 128 + (((quad    ) ^ (r & 7)) << 4));
            pa1[sub] = *(const bs8*)(pbuf + r * 128 + (((quad + 4) ^ (r & 7)) << 4));
            lacc[sub] = MFMA16(pa0[sub], ones, lacc[sub]);
            lacc[sub] = MFMA16(pa1[sub], ones, lacc[sub]);
        }

        // O += P.V  (4 ct of 16 channels each, V already in registers)
        __builtin_amdgcn_s_setprio(1);
#pragma unroll
        for (int ct = 0; ct < 4; ct++) {
            bs8 v0 = vb[ct][0], v1 = vb[ct][1];
#pragma unroll
            for (int sub = 0; sub < 4; sub++) {
                oacc[sub][ct] = MFMA16(pa0[sub], v0, oacc[sub][ct]);
                oacc[sub][ct] = MFMA16(pa1[sub], v1, oacc[sub][ct]);
            }
        }
        __builtin_amdgcn_s_setprio(0);

        kb0 = nk0; kb1 = nk1;
    }

    // ---- epilogue: out = gamma*O/l + x ----
    const float g = gamma[0];
#pragma unroll
    for (int sub = 0; sub < 4; sub++) {
        float inv0 = g / lacc[sub][0];
        float inv1 = g / lacc[sub][1];
        float inv2 = g / lacc[sub][2];
        float inv3 = g / lacc[sub][3];
#pragma unroll
        for (int ct = 0; ct < 4; ct++) {
            int c = ch0 + wave * 64 + ct * 16 + l16;
            int n = i0 + sub * 16 + quad * 4;
            size_t idx = ((size_t)b * C_ + c) * N_ + n;
            float4 xv = *(const float4*)(x + idx);
            float4 o;
            o.x = oacc[sub][ct][0] * inv0 + xv.x;
            o.y = oacc[sub][ct][1] * inv1 + xv.y;
            o.z = oacc[sub][ct][2] * inv2 + xv.z;
            o.w = oacc[sub][ct][3] * inv3 + xv.w;
            *(float4*)(out + idx) = o;
        }
    }
}

// ---------------------------------------------------------------------------
extern "C" void kernel_launch(void* const* d_in, const int* in_sizes, int n_in,
                              void* d_out, int out_size, void* d_ws, size_t ws_size,
                              hipStream_t stream)
{
    const float* x     = (const float*)d_in[0];
    const float* Wq    = (const float*)d_in[1];
    const float* bq    = (const float*)d_in[2];
    const float* Wk    = (const float*)d_in[3];
    const float* bk    = (const float*)d_in[4];
    const float* Wv    = (const float*)d_in[5];
    const float* bv    = (const float*)d_in[6];
    const float* gamma = (const float*)d_in[7];
    float* out = (float*)d_out;

    dim3 blk(256);

    const size_t szXT = (size_t)B_ * N_ * C_ * sizeof(bf16);   // 33,554,432
    const size_t szQ  = (size_t)B_ * N_ * CQ_ * sizeof(bf16);  //  4,194,304
    const size_t szVt = szXT;                                  // 33,554,432
    const size_t szWq = (size_t)CQ_ * C_ * sizeof(bf16);       //     65,536
    const size_t szWv = (size_t)C_ * C_ * sizeof(bf16);        //    524,288
    const size_t need_full = szXT + 2 * szQ + szVt + 2 * szWq + szWv; // ~72.6 MB

    if (ws_size >= need_full) {
        char* ws = (char*)d_ws;
        bf16* xT  = (bf16*)ws;
        bf16* Q   = (bf16*)(ws + szXT);
        bf16* K   = (bf16*)(ws + szXT + szQ);
        bf16* Vt  = (bf16*)(ws + szXT + 2 * szQ);
        bf16* Wqb = (bf16*)(ws + szXT + 2 * szQ + szVt);
        bf16* Wkb = (bf16*)((char*)Wqb + szWq);
        bf16* Wvb = (bf16*)((char*)Wkb + szWq);

        cast_weights<<<dim3(320), blk, 0, stream>>>(Wq, Wk, Wv, Wqb, Wkb, Wvb);
        cast_transpose<<<dim3(64, 8, B_), blk, 0, stream>>>(x, xT);

        mfma_gemm<0><<<dim3(64, 1, B_), blk, 0, stream>>>(xT, Wqb, bq, Q);
        mfma_gemm<0><<<dim3(64, 1, B_), blk, 0, stream>>>(xT, Wkb, bk, K);
        mfma_gemm<1><<<dim3(64, 8, B_), blk, 0, stream>>>(xT, Wvb, bv, Vt);

        attn_fused<<<dim3(B_, 64, 2), blk, 0, stream>>>(Q, K, Vt, x, gamma, out);
    } else {
        // Per-batch chunked fallback
        const size_t xtb = (size_t)N_ * C_ * sizeof(bf16);
        const size_t qb  = (size_t)N_ * CQ_ * sizeof(bf16);
        char* ws = (char*)d_ws;
        bf16* Wqb = (bf16*)ws;
        bf16* Wkb = (bf16*)(ws + szWq);
        bf16* Wvb = (bf16*)(ws + 2 * szWq);
        bf16* xT  = (bf16*)(ws + 2 * szWq + szWv);
        bf16* Q   = (bf16*)((char*)xT + xtb);
        bf16* K   = (bf16*)((char*)Q + qb);
        bf16* Vt  = (bf16*)((char*)K + qb);

        cast_weights<<<dim3(320), blk, 0, stream>>>(Wq, Wk, Wv, Wqb, Wkb, Wvb);

        for (int b = 0; b < B_; b++) {
            const float* xb = x + (size_t)b * C_ * N_;
            float*       ob = out + (size_t)b * C_ * N_;
            cast_transpose<<<dim3(64, 8, 1), blk, 0, stream>>>(xb, xT);
            mfma_gemm<0><<<dim3(64, 1, 1), blk, 0, stream>>>(xT, Wqb, bq, Q);
            mfma_gemm<0><<<dim3(64, 1, 1), blk, 0, stream>>>(xT, Wkb, bk, K);
            mfma_gemm<1><<<dim3(64, 8, 1), blk, 0, stream>>>(xT, Wvb, bv, Vt);
            attn_fused<<<dim3(1, 64, 2), blk, 0, stream>>>(Q, K, Vt, xb, gamma, ob);
        }
    }
}